// Round 7
// baseline (200.330 us; speedup 1.0000x reference)
//
#include <hip/hip_runtime.h>

#define N_BINS 100
#define BLOCK 1024
#define GRID 512           // 2 blocks/CU x 16 waves = 32 waves/CU
#define NPART GRID         // one partial histogram column per block
#define EPS 1e-4f          // boundary uncertainty band; analytic fma error < 3e-5

// classify 4 values; CONSUME(g_int, inc_allowed) is either an LDS atomic or a keepalive
#define CLASSIFY4(v, CONSUME_FAST, CONSUME_SLOW)                                             \
    {                                                                                        \
        float f0 = fmaf(v.x, scale, c0), f1 = fmaf(v.y, scale, c0);                          \
        float f2 = fmaf(v.z, scale, c0), f3 = fmaf(v.w, scale, c0);                          \
        bool unc = (fabsf(f0 - rintf(f0)) < EPS) | (f0 <= EPS) | (f0 >= (float)N_BINS - EPS) | \
                   (fabsf(f1 - rintf(f1)) < EPS) | (f1 <= EPS) | (f1 >= (float)N_BINS - EPS) | \
                   (fabsf(f2 - rintf(f2)) < EPS) | (f2 <= EPS) | (f2 >= (float)N_BINS - EPS) | \
                   (fabsf(f3 - rintf(f3)) < EPS) | (f3 <= EPS) | (f3 >= (float)N_BINS - EPS);  \
        if (__any(unc)) {                                                                    \
            float vals[4] = {v.x, v.y, v.z, v.w};                                            \
            _Pragma("unroll") for (int k = 0; k < 4; ++k) {                                  \
                float val = vals[k];                                                         \
                int g = min(max((int)fmaf(val, scale, c0), 0), N_BINS - 1);                  \
                while (g > 0 && val <= sb[g]) --g;                                           \
                while (g < N_BINS - 1 && val > sb[g + 1]) ++g;                               \
                int ok = (val > b0 && val <= bN) ? 1 : 0;                                    \
                CONSUME_SLOW(g, ok);                                                         \
            }                                                                                \
        } else {                                                                             \
            int g0 = (int)f0, g1 = (int)f1, g2 = (int)f2, g3 = (int)f3;                      \
            CONSUME_FAST(g0); CONSUME_FAST(g1); CONSUME_FAST(g2); CONSUME_FAST(g3);          \
        }                                                                                    \
    }

// ---------------- real histogram: LDS bank-private, NO global atomics ----------------
__global__ __launch_bounds__(BLOCK) void hist_kernel(const float* __restrict__ x,
                                                     const float* __restrict__ bounds,
                                                     float* __restrict__ part, int n) {
    __shared__ float sb[N_BINS + 1];
    __shared__ unsigned int sh[N_BINS][32];
    const int tid = threadIdx.x;
    const int col = tid & 31;

    if (tid < N_BINS + 1) sb[tid] = bounds[tid];
    for (int i = tid; i < N_BINS * 32; i += BLOCK) ((unsigned int*)sh)[i] = 0u;
    __syncthreads();

    const float b0 = sb[0], bN = sb[N_BINS];
    const float scale = (float)N_BINS / (bN - b0);
    const float c0 = -b0 * scale;

#define FAST_AT(g)     atomicAdd(&sh[g][col], 1u)
#define SLOW_AT(g, ok) atomicAdd(&sh[g][col], (unsigned int)(ok))

    const int n4 = n >> 2;
    const float4* __restrict__ x4 = (const float4*)x;
    const int gstride = GRID * BLOCK;
    int i = blockIdx.x * BLOCK + tid;

    for (; i + 3 * gstride < n4; i += 4 * gstride) {   // 4 independent loads in flight
        float4 v0 = x4[i];
        float4 v1 = x4[i + gstride];
        float4 v2 = x4[i + 2 * gstride];
        float4 v3 = x4[i + 3 * gstride];
        CLASSIFY4(v0, FAST_AT, SLOW_AT);
        CLASSIFY4(v1, FAST_AT, SLOW_AT);
        CLASSIFY4(v2, FAST_AT, SLOW_AT);
        CLASSIFY4(v3, FAST_AT, SLOW_AT);
    }
    for (; i < n4; i += gstride) { float4 v = x4[i]; CLASSIFY4(v, FAST_AT, SLOW_AT); }
    for (int t = (n4 << 2) + blockIdx.x * BLOCK + tid; t < n; t += gstride) {
        float val = x[t];
        int g = min(max((int)fmaf(val, scale, c0), 0), N_BINS - 1);
        while (g > 0 && val <= sb[g]) --g;
        while (g < N_BINS - 1 && val > sb[g + 1]) ++g;
        if (val > b0 && val <= bN) atomicAdd(&sh[g][col], 1u);
    }
#undef FAST_AT
#undef SLOW_AT

    __syncthreads();
    // flush: plain store of this block's 100 partial sums (layout [bin][NPART])
    if (tid < N_BINS) {
        unsigned int c = 0;
        #pragma unroll
        for (int j = 0; j < 32; ++j) c += sh[tid][(j + tid) & 31];
        part[tid * NPART + blockIdx.x] = (float)c;
    }
}

// ---------------- final reduce: bin g = sum of its 512 partials ----------------
__global__ __launch_bounds__(256) void reduce_kernel(const float* __restrict__ part,
                                                     float* __restrict__ out) {
    const int g = blockIdx.x;
    const int tid = threadIdx.x;
    __shared__ float red[4];
    float s = part[g * NPART + tid] + part[g * NPART + tid + 256];
    #pragma unroll
    for (int off = 32; off > 0; off >>= 1) s += __shfl_down(s, off);
    if ((tid & 63) == 0) red[tid >> 6] = s;
    __syncthreads();
    if (tid == 0) out[g] = red[0] + red[1] + red[2] + red[3];
}

// ---------------- ablation: loads + classify only (atomics -> keepalive), x4 ----------------
__global__ __launch_bounds__(BLOCK) void ablate_stream_kernel(const float* __restrict__ x,
                                                              const float* __restrict__ bounds,
                                                              int n) {
    __shared__ float sb[N_BINS + 1];
    const int tid = threadIdx.x;
    if (tid < N_BINS + 1) sb[tid] = bounds[tid];
    __syncthreads();
    const float b0 = sb[0], bN = sb[N_BINS];
    const float scale = (float)N_BINS / (bN - b0);
    const float c0 = -b0 * scale;

#define FAST_KA(g)     asm volatile("" ::"v"(g))
#define SLOW_KA(g, ok) asm volatile("" ::"v"(g), "v"(ok))

    const int n4 = n >> 2;
    const float4* __restrict__ x4 = (const float4*)x;
    const int gstride = GRID * BLOCK;

    for (int r = 0; r < 4; ++r) {
        // rotate block offset per repeat so addresses differ (defeats cross-repeat load CSE)
        int i = ((blockIdx.x + r * 128) % GRID) * BLOCK + tid;
        for (; i + 3 * gstride < n4; i += 4 * gstride) {
            float4 v0 = x4[i];
            float4 v1 = x4[i + gstride];
            float4 v2 = x4[i + 2 * gstride];
            float4 v3 = x4[i + 3 * gstride];
            CLASSIFY4(v0, FAST_KA, SLOW_KA);
            CLASSIFY4(v1, FAST_KA, SLOW_KA);
            CLASSIFY4(v2, FAST_KA, SLOW_KA);
            CLASSIFY4(v3, FAST_KA, SLOW_KA);
        }
        for (; i < n4; i += gstride) { float4 v = x4[i]; CLASSIFY4(v, FAST_KA, SLOW_KA); }
    }
#undef FAST_KA
#undef SLOW_KA
}

extern "C" void kernel_launch(void* const* d_in, const int* in_sizes, int n_in,
                              void* d_out, int out_size, void* d_ws, size_t ws_size,
                              hipStream_t stream) {
    const float* x = (const float*)d_in[0];
    const float* bounds = (const float*)d_in[1];
    float* out = (float*)d_out;
    float* part = (float*)d_ws;   // N_BINS * NPART floats = 204.8 KB, fully overwritten
    const int n = in_sizes[0];

    hist_kernel<<<GRID, BLOCK, 0, stream>>>(x, bounds, part, n);
    reduce_kernel<<<N_BINS, 256, 0, stream>>>(part, out);
    // instrumentation dispatch (measured via rocprof per-dispatch timing; remove next round)
    ablate_stream_kernel<<<GRID, BLOCK, 0, stream>>>(x, bounds, n);
}